// Round 1
// baseline (1119.695 us; speedup 1.0000x reference)
//
#include <hip/hip_runtime.h>
#include <stdint.h>

// Match XLA-CPU's unfused mul/add in the accept tests (reduce boundary flips).
#pragma clang fp contract(off)

#define NPTS 8192
#define KMIX 64
#define DDIM 64

// ---------------- threefry2x32 (exact transcription of jax/_src/prng.py) ----
__host__ __device__ __forceinline__ void tf2x32(uint32_t k0, uint32_t k1,
                                                uint32_t x0, uint32_t x1,
                                                uint32_t& o0, uint32_t& o1) {
  const uint32_t ks2 = k0 ^ k1 ^ 0x1BD11BDAu;
#define TF_R(r) { x0 += x1; x1 = (x1 << (r)) | (x1 >> (32 - (r))); x1 ^= x0; }
  x0 += k0; x1 += k1;
  TF_R(13) TF_R(15) TF_R(26) TF_R(6)
  x0 += k1; x1 += ks2 + 1u;
  TF_R(17) TF_R(29) TF_R(16) TF_R(24)
  x0 += ks2; x1 += k0 + 2u;
  TF_R(13) TF_R(15) TF_R(26) TF_R(6)
  x0 += k0; x1 += k1 + 3u;
  TF_R(17) TF_R(29) TF_R(16) TF_R(24)
  x0 += k1; x1 += ks2 + 4u;
  TF_R(13) TF_R(15) TF_R(26) TF_R(6)
  x0 += ks2; x1 += k0 + 5u;
#undef TF_R
  o0 = x0; o1 = x1;
}

// partitionable mode: subkey_i = threefry(key, (0,i)); bits_j = fold(r0^r1)
__device__ __forceinline__ uint32_t tf_bits_fold(uint32_t k0, uint32_t k1, uint32_t j) {
  uint32_t a, b; tf2x32(k0, k1, 0u, j, a, b); return a ^ b;
}

__device__ __forceinline__ float u01_from_bits(uint32_t bits) {
  // (bits>>9 | 0x3f800000).view(f32) - 1.0  ->  [0,1)
  return __uint_as_float((bits >> 9) | 0x3f800000u) - 1.0f;
}

// ---------------- XLA ErfInv32 (Giles polynomial, exact constants) ----------
__device__ float erfinv_f32(float x_) {
  float w = -log1pf(-x_ * x_);
  float p;
  if (w < 5.0f) {
    w = w - 2.5f;
    p = 2.81022636e-08f;
    p = 3.43273939e-07f + p * w;
    p = -3.5233877e-06f + p * w;
    p = -4.39150654e-06f + p * w;
    p = 0.00021858087f + p * w;
    p = -0.00125372503f + p * w;
    p = -0.00417768164f + p * w;
    p = 0.246640727f + p * w;
    p = 1.50140941f + p * w;
  } else {
    w = sqrtf(w) - 3.0f;
    p = -0.000200214257f;
    p = 0.000100950558f + p * w;
    p = 0.00134934322f + p * w;
    p = -0.00367342844f + p * w;
    p = 0.00573950773f + p * w;
    p = -0.0076224613f + p * w;
    p = 0.00943887047f + p * w;
    p = 1.00167406f + p * w;
    p = 2.83297682f + p * w;
  }
  return p * x_;
}

// jax.random.normal scalar: u = uniform(key,(),lo=nextafter(-1,0),hi=1); sqrt2*erfinv(u)
__device__ __forceinline__ float normal_scalar(uint32_t k0, uint32_t k1) {
  const float lo = __uint_as_float(0xBF7FFFFFu);   // -0.99999994 = nextafter(-1,0)
  float u = u01_from_bits(tf_bits_fold(k0, k1, 0u)) * 2.0f + lo;  // (hi-lo) rounds to 2.0f
  u = fmaxf(lo, u);
  return __uint_as_float(0x3FB504F3u) * erfinv_f32(u);            // f32(sqrt(2))
}

// ---------------- jax _gamma_one (Marsaglia-Tsang), partitionable splits ----
__device__ float gamma_one(uint32_t key0, uint32_t key1, float alpha_orig) {
  const bool boost_mask = alpha_orig >= 1.0f;
  const float alpha = boost_mask ? alpha_orig : (alpha_orig + 1.0f);
  const float d_ = alpha - 0.33333334f;            // f32(1/3)
  const float c_ = 0.33333334f / sqrtf(d_);

  // key, subkey = split(key); u_boost = uniform(subkey, ())
  uint32_t nk0, nk1, sk0, sk1;
  tf2x32(key0, key1, 0u, 0u, nk0, nk1);
  tf2x32(key0, key1, 0u, 1u, sk0, sk1);
  const float u_boost = u01_from_bits(tf_bits_fold(sk0, sk1, 0u));
  key0 = nk0; key1 = nk1;

  float X = 0.0f, V = 1.0f, U = 2.0f;  // initial state: cond true -> body runs >=1
  while ((U >= 1.0f - 0.0331f * (X * X) * (X * X)) &&
         (logf(U) >= 0.5f * X + d_ * ((1.0f - V) + logf(V)))) {
    // key, x_key, U_key = split(key, 3)
    uint32_t xk0, xk1, Uk0, Uk1;
    tf2x32(key0, key1, 0u, 0u, nk0, nk1);
    tf2x32(key0, key1, 0u, 1u, xk0, xk1);
    tf2x32(key0, key1, 0u, 2u, Uk0, Uk1);
    key0 = nk0; key1 = nk1;
    // inner: while v <= 0: key,sub = split(key); x = normal(sub); v = 1 + x*c
    float xx = 0.0f, vv = -1.0f;
    while (vv <= 0.0f) {
      uint32_t xn0, xn1, xs0, xs1;
      tf2x32(xk0, xk1, 0u, 0u, xn0, xn1);
      tf2x32(xk0, xk1, 0u, 1u, xs0, xs1);
      xk0 = xn0; xk1 = xn1;
      xx = normal_scalar(xs0, xs1);
      vv = 1.0f + xx * c_;
    }
    X = xx * xx;
    V = (vv * vv) * vv;
    U = u01_from_bits(tf_bits_fold(Uk0, Uk1, 0u));
  }
  float sample = d_ * V;
  if (!boost_mask) sample *= powf(u_boost, 1.0f / alpha_orig);
  return sample;
}

// ---------------- digamma (recurrence + asymptotic; x>=2 here) --------------
__device__ float digamma_f(float xf) {
  float r = 0.0f;
  while (xf < 6.0f) { r -= 1.0f / xf; xf += 1.0f; }
  const float inv = 1.0f / xf, inv2 = inv * inv;
  const float series = inv2 * (1.0f / 12.0f - inv2 * (1.0f / 120.0f - inv2 * (1.0f / 252.0f)));
  return r + logf(xf) - 0.5f * inv - series;
}

// ---------------- kernel A: deterministic KL term -> ws[0] ------------------
__global__ __launch_bounds__(256) void kl_kernel(
    const float* __restrict__ locs, const float* __restrict__ scales,
    const float* __restrict__ alpha, const float* __restrict__ beta,
    const float* __restrict__ counts, float* __restrict__ klout) {
  __shared__ double red[256];
  double acc = 0.0;
  for (int i = threadIdx.x; i < KMIX * DDIM; i += 256) {
    const float sc = scales[i], lc = locs[i];
    acc += (double)(-logf(sc) + 0.5f * (sc * sc + lc * lc) - 0.5f);
    const float a = alpha[i], b = beta[i];
    const float t = (a - 5.0f) * digamma_f(a) - lgammaf(a) + lgammaf(5.0f)
                  + 5.0f * (logf(b) - logf(5.0f)) + a * (5.0f - b) / b;
    acc += (double)t;
  }
  red[threadIdx.x] = acc;
  __syncthreads();
  for (int s = 128; s > 0; s >>= 1) {
    if (threadIdx.x < s) red[threadIdx.x] += red[threadIdx.x + s];
    __syncthreads();
  }
  if (threadIdx.x == 0) {
    double c0 = 0.0;
    for (int k = 0; k < KMIX; ++k) c0 += (double)counts[k];
    const float c0f = (float)c0;
    double th = (double)lgammaf(c0f) - (double)lgammaf(2.0f * (float)KMIX);
    for (int k = 0; k < KMIX; ++k) {
      const float ck = counts[k];
      th += -(double)lgammaf(ck) + (double)lgammaf(2.0f);
      th += (double)((ck - 2.0f) * (digamma_f(ck) - digamma_f(c0f)));
    }
    const double kl = red[0] + th;
    klout[0] = (float)(kl / (double)NPTS);
  }
}

// ---------------- kernel B: per-n wave; lane = component k ------------------
__global__ __launch_bounds__(256) void gmm_main(
    const float* __restrict__ x, const float* __restrict__ locs,
    const float* __restrict__ scales, const float* __restrict__ alpha,
    const float* __restrict__ beta, const float* __restrict__ counts,
    const float* __restrict__ klbuf, float* __restrict__ out,
    uint32_t ke0, uint32_t ke1, uint32_t kg0, uint32_t kg1,
    uint32_t kd0, uint32_t kd1) {
  const int w = threadIdx.x >> 6;
  const int lane = threadIdx.x & 63;
  const int n = blockIdx.x * 4 + w;
  const int k = lane;

  __shared__ float xs[4][DDIM];
  xs[w][lane] = x[n * DDIM + lane];
  __syncthreads();

  // gd ~ Gamma(counts[k]); per-sample key = threefry(kd, (0, n*K+k))
  const uint32_t nk = (uint32_t)(n * KMIX + k);
  float gd;
  {
    uint32_t a0, a1; tf2x32(kd0, kd1, 0u, nk, a0, a1);
    gd = gamma_one(a0, a1, counts[k]);
  }
  float ssum = gd;
  #pragma unroll
  for (int m = 32; m >= 1; m >>= 1) ssum += __shfl_xor(ssum, m, 64);
  const float log_theta = logf(gd / ssum);

  float sum_z2 = 0.0f, sum_logr = 0.0f;
  const uint32_t jbase = nk * (uint32_t)DDIM;
  const int krow = k * DDIM;
  const float lo = __uint_as_float(0xBF7FFFFFu);
  for (int dd = 0; dd < DDIM; ++dd) {
    const uint32_t j = jbase + (uint32_t)dd;
    // eps ~ Normal: counter-mode bits over full (N,K,D) array from ke
    float u = u01_from_bits(tf_bits_fold(ke0, ke1, j)) * 2.0f + lo;
    u = fmaxf(lo, u);
    const float eps = __uint_as_float(0x3FB504F3u) * erfinv_f32(u);
    const float mu = locs[krow + dd] + scales[krow + dd] * eps;
    // g ~ Gamma(alpha[k,d]); per-sample key = threefry(kg, (0, j))
    uint32_t c0w, c1w; tf2x32(kg0, kg1, 0u, j, c0w, c1w);
    const float g = gamma_one(c0w, c1w, alpha[krow + dd]);
    const float r = g / beta[krow + dd];       // sigma^-2
    const float diff = xs[w][dd] - mu;
    sum_z2 += diff * diff * r;
    sum_logr += logf(r);
  }
  // comp_lp = -0.5*sum z^2 - sum log(sigma) - 0.5*D*log(2pi)
  const float comp_lp = -0.5f * sum_z2 + 0.5f * sum_logr - 58.81206612509905f;
  float v = log_theta + comp_lp;

  // wave logsumexp over 64 components
  float m = v;
  #pragma unroll
  for (int mm = 32; mm >= 1; mm >>= 1) m = fmaxf(m, __shfl_xor(m, mm, 64));
  float e = expf(v - m);
  #pragma unroll
  for (int mm = 32; mm >= 1; mm >>= 1) e += __shfl_xor(e, mm, 64);
  const float log_lik = m + logf(e);

  if (lane == 0) out[n] = klbuf[0] - log_lik;
}

extern "C" void kernel_launch(void* const* d_in, const int* in_sizes, int n_in,
                              void* d_out, int out_size, void* d_ws, size_t ws_size,
                              hipStream_t stream) {
  (void)in_sizes; (void)n_in; (void)out_size; (void)ws_size;
  const float* x      = (const float*)d_in[0];
  const float* locs   = (const float*)d_in[1];
  const float* scales = (const float*)d_in[2];
  const float* alpha  = (const float*)d_in[3];
  const float* beta   = (const float*)d_in[4];
  const float* counts = (const float*)d_in[5];
  float* out   = (float*)d_out;
  float* klbuf = (float*)d_ws;

  // skey = jax.random.key(42) -> (0,42); ke,kg,kd = split(skey,3) fold-like:
  // subkey_i = threefry(skey, (0, i))
  uint32_t ke0, ke1, kg0, kg1, kd0, kd1;
  tf2x32(0u, 42u, 0u, 0u, ke0, ke1);
  tf2x32(0u, 42u, 0u, 1u, kg0, kg1);
  tf2x32(0u, 42u, 0u, 2u, kd0, kd1);

  hipLaunchKernelGGL(kl_kernel, dim3(1), dim3(256), 0, stream,
                     locs, scales, alpha, beta, counts, klbuf);
  hipLaunchKernelGGL(gmm_main, dim3(NPTS / 4), dim3(256), 0, stream,
                     x, locs, scales, alpha, beta, counts, klbuf, out,
                     ke0, ke1, kg0, kg1, kd0, kd1);
}

// Round 2
// 933.591 us; speedup vs baseline: 1.1993x; 1.1993x over previous
//
#include <hip/hip_runtime.h>
#include <stdint.h>

// Keep mul/add unfused everywhere (accept-test boundaries must not move).
#pragma clang fp contract(off)

#define NPTS 8192
#define KMIX 64
#define DDIM 64
#define TSTR 8   // table entry stride in floats: [loc,scale,c_,d_,rcpb,alpha,0,0]

// ---------------- threefry2x32 (exact transcription of jax/_src/prng.py) ----
__host__ __device__ __forceinline__ void tf2x32(uint32_t k0, uint32_t k1,
                                                uint32_t x0, uint32_t x1,
                                                uint32_t& o0, uint32_t& o1) {
  const uint32_t ks2 = k0 ^ k1 ^ 0x1BD11BDAu;
#define TF_R(r) { x0 += x1; x1 = (x1 << (r)) | (x1 >> (32 - (r))); x1 ^= x0; }
  x0 += k0; x1 += k1;
  TF_R(13) TF_R(15) TF_R(26) TF_R(6)
  x0 += k1; x1 += ks2 + 1u;
  TF_R(17) TF_R(29) TF_R(16) TF_R(24)
  x0 += ks2; x1 += k0 + 2u;
  TF_R(13) TF_R(15) TF_R(26) TF_R(6)
  x0 += k0; x1 += k1 + 3u;
  TF_R(17) TF_R(29) TF_R(16) TF_R(24)
  x0 += k1; x1 += ks2 + 4u;
  TF_R(13) TF_R(15) TF_R(26) TF_R(6)
  x0 += ks2; x1 += k0 + 5u;
#undef TF_R
  o0 = x0; o1 = x1;
}

// partitionable mode: bits_j = fold(r0^r1) of threefry(key, (0,j))
__device__ __forceinline__ uint32_t tf_bits_fold(uint32_t k0, uint32_t k1, uint32_t j) {
  uint32_t a, b; tf2x32(k0, k1, 0u, j, a, b); return a ^ b;
}

__device__ __forceinline__ float u01_from_bits(uint32_t bits) {
  return __uint_as_float((bits >> 9) | 0x3f800000u) - 1.0f;
}

// ---------------- XLA ErfInv32 (Giles polynomial, exact constants) ----------
__device__ float erfinv_f32(float x_) {
  float w = -log1pf(-x_ * x_);
  float p;
  if (w < 5.0f) {
    w = w - 2.5f;
    p = 2.81022636e-08f;
    p = 3.43273939e-07f + p * w;
    p = -3.5233877e-06f + p * w;
    p = -4.39150654e-06f + p * w;
    p = 0.00021858087f + p * w;
    p = -0.00125372503f + p * w;
    p = -0.00417768164f + p * w;
    p = 0.246640727f + p * w;
    p = 1.50140941f + p * w;
  } else {
    w = sqrtf(w) - 3.0f;
    p = -0.000200214257f;
    p = 0.000100950558f + p * w;
    p = 0.00134934322f + p * w;
    p = -0.00367342844f + p * w;
    p = 0.00573950773f + p * w;
    p = -0.0076224613f + p * w;
    p = 0.00943887047f + p * w;
    p = 1.00167406f + p * w;
    p = 2.83297682f + p * w;
  }
  return p * x_;
}

__device__ __forceinline__ float normal_scalar(uint32_t k0, uint32_t k1) {
  const float lo = __uint_as_float(0xBF7FFFFFu);   // nextafter(-1,0)
  float u = u01_from_bits(tf_bits_fold(k0, k1, 0u)) * 2.0f + lo;
  u = fmaxf(lo, u);
  return __uint_as_float(0x3FB504F3u) * erfinv_f32(u);  // f32(sqrt(2))
}

// ---------------- restructured _gamma_one: identical key-chain values, ------
// ---------------- unused computations skipped -------------------------------
__device__ float gamma_core(uint32_t key0, uint32_t key1, float d_, float c_,
                            float alpha_orig) {
  // key advance (always consumed by the loop)
  uint32_t nk0, nk1;
  tf2x32(key0, key1, 0u, 0u, nk0, nk1);
  const bool boost = alpha_orig >= 1.0f;
  float u_boost = 0.0f;
  if (!boost) {  // cold path: subkey + uniform only needed when alpha < 1
    uint32_t sk0, sk1;
    tf2x32(key0, key1, 0u, 1u, sk0, sk1);
    u_boost = u01_from_bits(tf_bits_fold(sk0, sk1, 0u));
  }
  key0 = nk0; key1 = nk1;

  float X, V, U;
  for (;;) {
    // split(key,3): x_key=(0,1), U_key=(0,2); key-advance (0,0) deferred to reject path
    uint32_t xk0, xk1, Uk0, Uk1;
    tf2x32(key0, key1, 0u, 1u, xk0, xk1);
    tf2x32(key0, key1, 0u, 2u, Uk0, Uk1);
    float xx, vv;
    for (;;) {
      uint32_t xs0, xs1;
      tf2x32(xk0, xk1, 0u, 1u, xs0, xs1);       // subkey of split(x_key)
      xx = normal_scalar(xs0, xs1);
      vv = 1.0f + xx * c_;
      if (vv > 0.0f) break;
      uint32_t t0, t1;                           // advance x_key only on retry
      tf2x32(xk0, xk1, 0u, 0u, t0, t1);
      xk0 = t0; xk1 = t1;
    }
    X = xx * xx;
    V = (vv * vv) * vv;
    U = u01_from_bits(tf_bits_fold(Uk0, Uk1, 0u));
    // EXACT round-0 accept expressions — do not modify.
    const bool rej = (U >= 1.0f - 0.0331f * (X * X) * (X * X)) &&
                     (logf(U) >= 0.5f * X + d_ * ((1.0f - V) + logf(V)));
    if (!rej) break;
    uint32_t t0, t1;                             // advance key only on reject
    tf2x32(key0, key1, 0u, 0u, t0, t1);
    key0 = t0; key1 = t1;
  }
  float sample = d_ * V;
  if (!boost) sample *= powf(u_boost, 1.0f / alpha_orig);
  return sample;
}

// ---------------- digamma (recurrence + asymptotic; x>=2 here) --------------
__device__ float digamma_f(float xf) {
  float r = 0.0f;
  while (xf < 6.0f) { r -= 1.0f / xf; xf += 1.0f; }
  const float inv = 1.0f / xf, inv2 = inv * inv;
  const float series = inv2 * (1.0f / 12.0f - inv2 * (1.0f / 120.0f - inv2 * (1.0f / 252.0f)));
  return r + logf(xf) - 0.5f * inv - series;
}

// ---------------- prep: KL term -> klout[0]; packed transposed table --------
__global__ __launch_bounds__(256) void prep_kernel(
    const float* __restrict__ locs, const float* __restrict__ scales,
    const float* __restrict__ alpha, const float* __restrict__ beta,
    const float* __restrict__ counts, float* __restrict__ klout,
    float* __restrict__ tab) {
  const int tid = threadIdx.x;
  __shared__ double red[256];
  double acc = 0.0;
  for (int i = tid; i < KMIX * DDIM; i += 256) {
    const int k = i >> 6, dd = i & 63;
    const float lc = locs[i], sc = scales[i], a = alpha[i], b = beta[i];
    acc += (double)(-logf(sc) + 0.5f * (sc * sc + lc * lc) - 0.5f);
    const float t = (a - 5.0f) * digamma_f(a) - lgammaf(a) + lgammaf(5.0f)
                  + 5.0f * (logf(b) - logf(5.0f)) + a * (5.0f - b) / b;
    acc += (double)t;
    // table, transposed to [dd][k] so lane=k loads coalesce
    const float al = (a >= 1.0f) ? a : a + 1.0f;
    const float d_ = al - 0.33333334f;                  // == gamma_core's d_
    const float c_ = 0.33333334f / sqrtf(d_);           // bit-identical expr
    float* e = tab + ((size_t)((dd << 6) | k)) * TSTR;
    e[0] = lc; e[1] = sc; e[2] = c_; e[3] = d_;
    e[4] = 1.0f / b; e[5] = a; e[6] = 0.0f; e[7] = 0.0f;
  }
  red[tid] = acc;
  __syncthreads();
  for (int s = 128; s > 0; s >>= 1) {
    if (tid < s) red[tid] += red[tid + s];
    __syncthreads();
  }
  if (tid == 0) {
    double c0 = 0.0;
    for (int k = 0; k < KMIX; ++k) c0 += (double)counts[k];
    const float c0f = (float)c0;
    double th = (double)lgammaf(c0f) - (double)lgammaf(2.0f * (float)KMIX);
    for (int k = 0; k < KMIX; ++k) {
      const float ck = counts[k];
      th += -(double)lgammaf(ck) + (double)lgammaf(2.0f);
      th += (double)((ck - 2.0f) * (digamma_f(ck) - digamma_f(c0f)));
    }
    const double kl = red[0] + th;
    klout[0] = (float)(kl / (double)NPTS);
  }
}

// ---------------- main: 1 wave per n; lane = component k --------------------
__global__ __launch_bounds__(256) void gmm_main(
    const float* __restrict__ x, const float* __restrict__ counts,
    const float* __restrict__ klbuf, const float* __restrict__ tab,
    float* __restrict__ out,
    uint32_t ke0, uint32_t ke1, uint32_t kg0, uint32_t kg1,
    uint32_t kd0, uint32_t kd1) {
  const int w = threadIdx.x >> 6;
  const int lane = threadIdx.x & 63;
  const int n = blockIdx.x * 4 + w;
  const int k = lane;

  __shared__ float xsh[4][DDIM];
  xsh[w][lane] = x[n * DDIM + lane];
  __syncthreads();

  const uint32_t nk = (uint32_t)(n * KMIX + k);

  // Dirichlet gamma: gd ~ Gamma(counts[k]); key = threefry(kd, (0, nk))
  float gd;
  {
    const float ck = counts[k];
    const float al = (ck >= 1.0f) ? ck : ck + 1.0f;
    const float d_ = al - 0.33333334f;
    const float c_ = 0.33333334f / sqrtf(d_);
    uint32_t a0, a1; tf2x32(kd0, kd1, 0u, nk, a0, a1);
    gd = gamma_core(a0, a1, d_, c_, ck);
  }
  float ssum = gd;
  #pragma unroll
  for (int m = 32; m >= 1; m >>= 1) ssum += __shfl_xor(ssum, m, 64);
  const float log_theta = logf(gd / ssum);

  float sum_z2 = 0.0f;
  float prod_r = 1.0f;
  const uint32_t jbase = nk << 6;
  const float lo = __uint_as_float(0xBF7FFFFFu);
  for (int dd = 0; dd < DDIM; ++dd) {
    const float* e = tab + ((size_t)((dd << 6) | k)) * TSTR;
    const float4 t0 = *(const float4*)(e);      // {loc, scale, c_, d_}
    const float4 t1 = *(const float4*)(e + 4);  // {rcpb, alpha, 0, 0}
    const uint32_t j = jbase + (uint32_t)dd;
    // eps ~ Normal (counter-mode bits over (N,K,D) from ke)
    float u = u01_from_bits(tf_bits_fold(ke0, ke1, j)) * 2.0f + lo;
    u = fmaxf(lo, u);
    const float eps = __uint_as_float(0x3FB504F3u) * erfinv_f32(u);
    const float mu = t0.x + t0.y * eps;
    // g ~ Gamma(alpha[k,dd]); key = threefry(kg, (0, j))
    uint32_t c0w, c1w; tf2x32(kg0, kg1, 0u, j, c0w, c1w);
    const float g = gamma_core(c0w, c1w, t0.w, t0.z, t1.y);
    const float r = g * t1.x;                    // g * (1/beta)
    const float diff = xsh[w][dd] - mu;
    sum_z2 += diff * diff * r;
    prod_r *= r;                                 // sum(log r) -> log(prod r)
  }
  const float comp_lp = -0.5f * sum_z2 + 0.5f * logf(prod_r) - 58.81206612509905f;
  float v = log_theta + comp_lp;

  float m = v;
  #pragma unroll
  for (int mm = 32; mm >= 1; mm >>= 1) m = fmaxf(m, __shfl_xor(m, mm, 64));
  float e2 = expf(v - m);
  #pragma unroll
  for (int mm = 32; mm >= 1; mm >>= 1) e2 += __shfl_xor(e2, mm, 64);
  const float log_lik = m + logf(e2);

  if (lane == 0) out[n] = klbuf[0] - log_lik;
}

extern "C" void kernel_launch(void* const* d_in, const int* in_sizes, int n_in,
                              void* d_out, int out_size, void* d_ws, size_t ws_size,
                              hipStream_t stream) {
  (void)in_sizes; (void)n_in; (void)out_size; (void)ws_size;
  const float* x      = (const float*)d_in[0];
  const float* locs   = (const float*)d_in[1];
  const float* scales = (const float*)d_in[2];
  const float* alpha  = (const float*)d_in[3];
  const float* beta   = (const float*)d_in[4];
  const float* counts = (const float*)d_in[5];
  float* out   = (float*)d_out;
  float* klbuf = (float*)d_ws;
  float* tab   = (float*)((char*)d_ws + 1024);   // 4096 * 8 floats = 128 KiB

  uint32_t ke0, ke1, kg0, kg1, kd0, kd1;
  tf2x32(0u, 42u, 0u, 0u, ke0, ke1);
  tf2x32(0u, 42u, 0u, 1u, kg0, kg1);
  tf2x32(0u, 42u, 0u, 2u, kd0, kd1);

  hipLaunchKernelGGL(prep_kernel, dim3(1), dim3(256), 0, stream,
                     locs, scales, alpha, beta, counts, klbuf, tab);
  hipLaunchKernelGGL(gmm_main, dim3(NPTS / 4), dim3(256), 0, stream,
                     x, counts, klbuf, tab, out,
                     ke0, ke1, kg0, kg1, kd0, kd1);
}

// Round 3
// 757.994 us; speedup vs baseline: 1.4772x; 1.2317x over previous
//
#include <hip/hip_runtime.h>
#include <stdint.h>

// Keep mul/add unfused everywhere (accept-test boundaries must not move).
#pragma clang fp contract(off)

#define NPTS 8192
#define KMIX 64
#define DDIM 64
#define TSTR 8    // param table entry stride (floats)
#define QCAP 4    // deferred-retry slots per lane
#define QW   6    // words per slot: key0,key1,diff2,rcpb,d_,c_
#define LSTR 26   // padded per-lane queue stride in words (8B-aligned, bank-spread)

// ---------------- threefry2x32 (exact transcription of jax/_src/prng.py) ----
__host__ __device__ __forceinline__ void tf2x32(uint32_t k0, uint32_t k1,
                                                uint32_t x0, uint32_t x1,
                                                uint32_t& o0, uint32_t& o1) {
  const uint32_t ks2 = k0 ^ k1 ^ 0x1BD11BDAu;
#define TF_R(r) { x0 += x1; x1 = (x1 << (r)) | (x1 >> (32 - (r))); x1 ^= x0; }
  x0 += k0; x1 += k1;
  TF_R(13) TF_R(15) TF_R(26) TF_R(6)
  x0 += k1; x1 += ks2 + 1u;
  TF_R(17) TF_R(29) TF_R(16) TF_R(24)
  x0 += ks2; x1 += k0 + 2u;
  TF_R(13) TF_R(15) TF_R(26) TF_R(6)
  x0 += k0; x1 += k1 + 3u;
  TF_R(17) TF_R(29) TF_R(16) TF_R(24)
  x0 += k1; x1 += ks2 + 4u;
  TF_R(13) TF_R(15) TF_R(26) TF_R(6)
  x0 += ks2; x1 += k0 + 5u;
#undef TF_R
  o0 = x0; o1 = x1;
}

__device__ __forceinline__ uint32_t tf_bits_fold(uint32_t k0, uint32_t k1, uint32_t j) {
  uint32_t a, b; tf2x32(k0, k1, 0u, j, a, b); return a ^ b;
}

__device__ __forceinline__ float u01_from_bits(uint32_t bits) {
  return __uint_as_float((bits >> 9) | 0x3f800000u) - 1.0f;
}

// ---------------- XLA ErfInv32 (Giles polynomial, exact constants) ----------
__device__ float erfinv_f32(float x_) {
  float w = -log1pf(-x_ * x_);
  float p;
  if (w < 5.0f) {
    w = w - 2.5f;
    p = 2.81022636e-08f;
    p = 3.43273939e-07f + p * w;
    p = -3.5233877e-06f + p * w;
    p = -4.39150654e-06f + p * w;
    p = 0.00021858087f + p * w;
    p = -0.00125372503f + p * w;
    p = -0.00417768164f + p * w;
    p = 0.246640727f + p * w;
    p = 1.50140941f + p * w;
  } else {
    w = sqrtf(w) - 3.0f;
    p = -0.000200214257f;
    p = 0.000100950558f + p * w;
    p = 0.00134934322f + p * w;
    p = -0.00367342844f + p * w;
    p = 0.00573950773f + p * w;
    p = -0.0076224613f + p * w;
    p = 0.00943887047f + p * w;
    p = 1.00167406f + p * w;
    p = 2.83297682f + p * w;
  }
  return p * x_;
}

__device__ __forceinline__ float normal_scalar(uint32_t k0, uint32_t k1) {
  const float lo = __uint_as_float(0xBF7FFFFFu);   // nextafter(-1,0)
  float u = u01_from_bits(tf_bits_fold(k0, k1, 0u)) * 2.0f + lo;
  u = fmaxf(lo, u);
  return __uint_as_float(0x3FB504F3u) * erfinv_f32(u);  // f32(sqrt(2))
}

// ---- continue a rejected gamma chain to acceptance (carried key just rejected)
__device__ float gamma_finish(uint32_t key0, uint32_t key1, float d_, float c_) {
  float X, V, U;
  for (;;) {
    uint32_t t0, t1;                       // key advance (split's new key)
    tf2x32(key0, key1, 0u, 0u, t0, t1);
    key0 = t0; key1 = t1;
    uint32_t xk0, xk1, Uk0, Uk1;
    tf2x32(key0, key1, 0u, 1u, xk0, xk1);
    tf2x32(key0, key1, 0u, 2u, Uk0, Uk1);
    float xx, vv;
    for (;;) {
      uint32_t xs0, xs1;
      tf2x32(xk0, xk1, 0u, 1u, xs0, xs1);
      xx = normal_scalar(xs0, xs1);
      vv = 1.0f + xx * c_;
      if (vv > 0.0f) break;
      uint32_t a0, a1;
      tf2x32(xk0, xk1, 0u, 0u, a0, a1);
      xk0 = a0; xk1 = a1;
    }
    X = xx * xx;
    V = (vv * vv) * vv;
    U = u01_from_bits(tf_bits_fold(Uk0, Uk1, 0u));
    // EXACT round-0 accept expressions — do not modify.
    const bool rej = (U >= 1.0f - 0.0331f * (X * X) * (X * X)) &&
                     (logf(U) >= 0.5f * X + d_ * ((1.0f - V) + logf(V)));
    if (!rej) break;
  }
  return d_ * V;
}

// ---- generic _gamma_one (Dirichlet + alpha<1 fallback) ---------------------
__device__ float gamma_core(uint32_t key0, uint32_t key1, float d_, float c_,
                            float alpha_orig) {
  uint32_t nk0, nk1;
  tf2x32(key0, key1, 0u, 0u, nk0, nk1);
  const bool boost = alpha_orig >= 1.0f;
  float u_boost = 0.0f;
  if (!boost) {
    uint32_t sk0, sk1;
    tf2x32(key0, key1, 0u, 1u, sk0, sk1);
    u_boost = u01_from_bits(tf_bits_fold(sk0, sk1, 0u));
  }
  key0 = nk0; key1 = nk1;

  float X, V, U;
  for (;;) {
    uint32_t xk0, xk1, Uk0, Uk1;
    tf2x32(key0, key1, 0u, 1u, xk0, xk1);
    tf2x32(key0, key1, 0u, 2u, Uk0, Uk1);
    float xx, vv;
    for (;;) {
      uint32_t xs0, xs1;
      tf2x32(xk0, xk1, 0u, 1u, xs0, xs1);
      xx = normal_scalar(xs0, xs1);
      vv = 1.0f + xx * c_;
      if (vv > 0.0f) break;
      uint32_t t0, t1;
      tf2x32(xk0, xk1, 0u, 0u, t0, t1);
      xk0 = t0; xk1 = t1;
    }
    X = xx * xx;
    V = (vv * vv) * vv;
    U = u01_from_bits(tf_bits_fold(Uk0, Uk1, 0u));
    const bool rej = (U >= 1.0f - 0.0331f * (X * X) * (X * X)) &&
                     (logf(U) >= 0.5f * X + d_ * ((1.0f - V) + logf(V)));
    if (!rej) break;
    uint32_t t0, t1;
    tf2x32(key0, key1, 0u, 0u, t0, t1);
    key0 = t0; key1 = t1;
  }
  float sample = d_ * V;
  if (!boost) sample *= powf(u_boost, 1.0f / alpha_orig);
  return sample;
}

// ---------------- digamma (recurrence + asymptotic; x>=2 here) --------------
__device__ float digamma_f(float xf) {
  float r = 0.0f;
  while (xf < 6.0f) { r -= 1.0f / xf; xf += 1.0f; }
  const float inv = 1.0f / xf, inv2 = inv * inv;
  const float series = inv2 * (1.0f / 12.0f - inv2 * (1.0f / 120.0f - inv2 * (1.0f / 252.0f)));
  return r + logf(xf) - 0.5f * inv - series;
}

// ---------------- prep: KL term -> klout[0]; packed transposed table --------
__global__ __launch_bounds__(256) void prep_kernel(
    const float* __restrict__ locs, const float* __restrict__ scales,
    const float* __restrict__ alpha, const float* __restrict__ beta,
    const float* __restrict__ counts, float* __restrict__ klout,
    float* __restrict__ tab) {
  const int tid = threadIdx.x;
  __shared__ double red[256];
  double acc = 0.0;
  for (int i = tid; i < KMIX * DDIM; i += 256) {
    const int k = i >> 6, dd = i & 63;
    const float lc = locs[i], sc = scales[i], a = alpha[i], b = beta[i];
    acc += (double)(-logf(sc) + 0.5f * (sc * sc + lc * lc) - 0.5f);
    const float t = (a - 5.0f) * digamma_f(a) - lgammaf(a) + lgammaf(5.0f)
                  + 5.0f * (logf(b) - logf(5.0f)) + a * (5.0f - b) / b;
    acc += (double)t;
    const float al = (a >= 1.0f) ? a : a + 1.0f;
    const float d_ = al - 0.33333334f;                  // bit-identical to gamma path
    const float c_ = 0.33333334f / sqrtf(d_);
    float* e = tab + ((size_t)((dd << 6) | k)) * TSTR;
    e[0] = lc; e[1] = sc; e[2] = c_; e[3] = d_;
    e[4] = 1.0f / b; e[5] = a; e[6] = 0.0f; e[7] = 0.0f;
  }
  red[tid] = acc;
  __syncthreads();
  for (int s = 128; s > 0; s >>= 1) {
    if (tid < s) red[tid] += red[tid + s];
    __syncthreads();
  }
  if (tid == 0) {
    double c0 = 0.0;
    for (int k = 0; k < KMIX; ++k) c0 += (double)counts[k];
    const float c0f = (float)c0;
    double th = (double)lgammaf(c0f) - (double)lgammaf(2.0f * (float)KMIX);
    for (int k = 0; k < KMIX; ++k) {
      const float ck = counts[k];
      th += -(double)lgammaf(ck) + (double)lgammaf(2.0f);
      th += (double)((ck - 2.0f) * (digamma_f(ck) - digamma_f(c0f)));
    }
    const double kl = red[0] + th;
    klout[0] = (float)(kl / (double)NPTS);
  }
}

// ---------------- main: 1 wave per n; lane = k; deferred-retry queue --------
__global__ __launch_bounds__(256) void gmm_main(
    const float* __restrict__ x, const float* __restrict__ counts,
    const float* __restrict__ klbuf, const float* __restrict__ tab,
    float* __restrict__ out,
    uint32_t ke0, uint32_t ke1, uint32_t kg0, uint32_t kg1,
    uint32_t kd0, uint32_t kd1) {
  const int w = threadIdx.x >> 6;
  const int lane = threadIdx.x & 63;
  const int n = blockIdx.x * 4 + w;
  const int k = lane;

  __shared__ float xsh[4][DDIM];
  __shared__ uint32_t q[4][64][LSTR];   // per-lane deferred-retry queue (padded)
  xsh[w][lane] = x[n * DDIM + lane];
  __syncthreads();
  uint32_t* const myq = &q[w][lane][0];
  int cnt = 0;

  const uint32_t nk = (uint32_t)(n * KMIX + k);

  // Dirichlet gamma: gd ~ Gamma(counts[k]); key = threefry(kd, (0, nk))
  float gd;
  {
    const float ck = counts[k];
    const float al = (ck >= 1.0f) ? ck : ck + 1.0f;
    const float d_ = al - 0.33333334f;
    const float c_ = 0.33333334f / sqrtf(d_);
    uint32_t a0, a1; tf2x32(kd0, kd1, 0u, nk, a0, a1);
    gd = gamma_core(a0, a1, d_, c_, ck);
  }
  float ssum = gd;
  #pragma unroll
  for (int m = 32; m >= 1; m >>= 1) ssum += __shfl_xor(ssum, m, 64);
  const float log_theta = logf(gd / ssum);

  float sum_z2 = 0.0f;
  float prod_r = 1.0f;
  const uint32_t jbase = nk << 6;
  const float lo = __uint_as_float(0xBF7FFFFFu);

  #pragma unroll 1
  for (int dd = 0; dd < DDIM; ++dd) {
    const float* e = tab + ((size_t)((dd << 6) | k)) * TSTR;
    const float4 t0 = *(const float4*)(e);      // {loc, scale, c_, d_}
    const float4 t1 = *(const float4*)(e + 4);  // {rcpb, alpha, 0, 0}
    const uint32_t j = jbase + (uint32_t)dd;

    // eps ~ Normal (counter-mode bits over (N,K,D) from ke) — output-only path
    float u = u01_from_bits(tf_bits_fold(ke0, ke1, j)) * 2.0f + lo;
    u = fmaxf(lo, u);
    const float eps = __uint_as_float(0x3FB504F3u) * erfinv_f32(u);
    const float mu = t0.x + t0.y * eps;
    const float diff = xsh[w][dd] - mu;
    const float diff2 = diff * diff;

    // gamma: first attempt inline; defer retries
    uint32_t gk0, gk1; tf2x32(kg0, kg1, 0u, j, gk0, gk1);
    float g;
    bool deferred = false;
    if (__builtin_expect(t1.y < 1.0f, 0)) {
      g = gamma_core(gk0, gk1, t0.w, t0.z, t1.y);   // never taken for this data
    } else {
      uint32_t key0, key1;
      tf2x32(gk0, gk1, 0u, 0u, key0, key1);         // initial split advance
      uint32_t xk0, xk1, Uk0, Uk1;
      tf2x32(key0, key1, 0u, 1u, xk0, xk1);
      tf2x32(key0, key1, 0u, 2u, Uk0, Uk1);
      float xx, vv;
      for (;;) {
        uint32_t xs0, xs1;
        tf2x32(xk0, xk1, 0u, 1u, xs0, xs1);
        xx = normal_scalar(xs0, xs1);
        vv = 1.0f + xx * t0.z;
        if (vv > 0.0f) break;
        uint32_t a0, a1;
        tf2x32(xk0, xk1, 0u, 0u, a0, a1);
        xk0 = a0; xk1 = a1;
      }
      const float X = xx * xx;
      const float V = (vv * vv) * vv;
      const float U = u01_from_bits(tf_bits_fold(Uk0, Uk1, 0u));
      const bool rej = (U >= 1.0f - 0.0331f * (X * X) * (X * X)) &&
                       (logf(U) >= 0.5f * X + t0.w * ((1.0f - V) + logf(V)));
      if (!rej) {
        g = t0.w * V;
      } else if (cnt < QCAP) {
        uint32_t* s = myq + cnt * QW;               // 8B-aligned slot
        s[0] = key0; s[1] = key1;
        s[2] = __float_as_uint(diff2); s[3] = __float_as_uint(t1.x);
        s[4] = __float_as_uint(t0.w);  s[5] = __float_as_uint(t0.z);
        ++cnt;
        deferred = true;
      } else {
        g = gamma_finish(key0, key1, t0.w, t0.z);   // rare overflow fallback
      }
    }
    if (!deferred) {
      const float r = g * t1.x;                     // g * (1/beta)
      sum_z2 += diff2 * r;
      prod_r *= r;
    }
  }

  // drain deferred retries: static slot index, dense lanes
  #pragma unroll 1
  for (int s = 0; s < QCAP; ++s) {
    if (__any(cnt > s)) {
      if (cnt > s) {
        const uint32_t* eq = myq + s * QW;
        const uint32_t K0 = eq[0], K1 = eq[1];
        const float diff2 = __uint_as_float(eq[2]);
        const float rcpb  = __uint_as_float(eq[3]);
        const float dq    = __uint_as_float(eq[4]);
        const float cq    = __uint_as_float(eq[5]);
        const float g = gamma_finish(K0, K1, dq, cq);
        const float r = g * rcpb;
        sum_z2 += diff2 * r;
        prod_r *= r;
      }
    }
  }

  const float comp_lp = -0.5f * sum_z2 + 0.5f * logf(prod_r) - 58.81206612509905f;
  float v = log_theta + comp_lp;

  float m = v;
  #pragma unroll
  for (int mm = 32; mm >= 1; mm >>= 1) m = fmaxf(m, __shfl_xor(m, mm, 64));
  float e2 = expf(v - m);
  #pragma unroll
  for (int mm = 32; mm >= 1; mm >>= 1) e2 += __shfl_xor(e2, mm, 64);
  const float log_lik = m + logf(e2);

  if (lane == 0) out[n] = klbuf[0] - log_lik;
}

extern "C" void kernel_launch(void* const* d_in, const int* in_sizes, int n_in,
                              void* d_out, int out_size, void* d_ws, size_t ws_size,
                              hipStream_t stream) {
  (void)in_sizes; (void)n_in; (void)out_size; (void)ws_size;
  const float* x      = (const float*)d_in[0];
  const float* locs   = (const float*)d_in[1];
  const float* scales = (const float*)d_in[2];
  const float* alpha  = (const float*)d_in[3];
  const float* beta   = (const float*)d_in[4];
  const float* counts = (const float*)d_in[5];
  float* out   = (float*)d_out;
  float* klbuf = (float*)d_ws;
  float* tab   = (float*)((char*)d_ws + 1024);   // 4096 * 8 floats = 128 KiB

  uint32_t ke0, ke1, kg0, kg1, kd0, kd1;
  tf2x32(0u, 42u, 0u, 0u, ke0, ke1);
  tf2x32(0u, 42u, 0u, 1u, kg0, kg1);
  tf2x32(0u, 42u, 0u, 2u, kd0, kd1);

  hipLaunchKernelGGL(prep_kernel, dim3(1), dim3(256), 0, stream,
                     locs, scales, alpha, beta, counts, klbuf, tab);
  hipLaunchKernelGGL(gmm_main, dim3(NPTS / 4), dim3(256), 0, stream,
                     x, counts, klbuf, tab, out,
                     ke0, ke1, kg0, kg1, kd0, kd1);
}

// Round 4
// 631.301 us; speedup vs baseline: 1.7736x; 1.2007x over previous
//
#include <hip/hip_runtime.h>
#include <stdint.h>

// Keep default mul/add unfused (accept-test boundaries); fast paths use fmaf explicitly.
#pragma clang fp contract(off)

#define NPTS 8192
#define KMIX 64
#define DDIM 64
#define TSTR 8    // param table entry stride (floats)
#define QCAP 6    // deferred-retry slots per lane
#define QW   4    // words per slot: key0,key1,diff2,dd
#define LSTR 25   // padded per-lane queue stride in words (odd -> bank-spread)

// ---------------- threefry2x32 (exact transcription of jax/_src/prng.py) ----
__host__ __device__ __forceinline__ void tf2x32(uint32_t k0, uint32_t k1,
                                                uint32_t x0, uint32_t x1,
                                                uint32_t& o0, uint32_t& o1) {
  const uint32_t ks2 = k0 ^ k1 ^ 0x1BD11BDAu;
#define TF_R(r) { x0 += x1; x1 = (x1 << (r)) | (x1 >> (32 - (r))); x1 ^= x0; }
  x0 += k0; x1 += k1;
  TF_R(13) TF_R(15) TF_R(26) TF_R(6)
  x0 += k1; x1 += ks2 + 1u;
  TF_R(17) TF_R(29) TF_R(16) TF_R(24)
  x0 += ks2; x1 += k0 + 2u;
  TF_R(13) TF_R(15) TF_R(26) TF_R(6)
  x0 += k0; x1 += k1 + 3u;
  TF_R(17) TF_R(29) TF_R(16) TF_R(24)
  x0 += k1; x1 += ks2 + 4u;
  TF_R(13) TF_R(15) TF_R(26) TF_R(6)
  x0 += ks2; x1 += k0 + 5u;
#undef TF_R
  o0 = x0; o1 = x1;
}

__device__ __forceinline__ uint32_t tf_bits_fold(uint32_t k0, uint32_t k1, uint32_t j) {
  uint32_t a, b; tf2x32(k0, k1, 0u, j, a, b); return a ^ b;
}

__device__ __forceinline__ float u01_from_bits(uint32_t bits) {
  return __uint_as_float((bits >> 9) | 0x3f800000u) - 1.0f;
}

// ---------------- fast erfinv: Giles constants, fmaf chain, hw log ----------
__device__ __forceinline__ float erfinv_fast(float x_) {
  float w = -__logf(1.0f - x_ * x_);
  float p;
  if (w < 5.0f) {
    w = w - 2.5f;
    p = fmaf(2.81022636e-08f, w, 3.43273939e-07f);
    p = fmaf(p, w, -3.5233877e-06f);
    p = fmaf(p, w, -4.39150654e-06f);
    p = fmaf(p, w, 0.00021858087f);
    p = fmaf(p, w, -0.00125372503f);
    p = fmaf(p, w, -0.00417768164f);
    p = fmaf(p, w, 0.246640727f);
    p = fmaf(p, w, 1.50140941f);
  } else {
    w = sqrtf(w) - 3.0f;
    p = fmaf(-0.000200214257f, w, 0.000100950558f);
    p = fmaf(p, w, 0.00134934322f);
    p = fmaf(p, w, -0.00367342844f);
    p = fmaf(p, w, 0.00573950773f);
    p = fmaf(p, w, -0.0076224613f);
    p = fmaf(p, w, 0.00943887047f);
    p = fmaf(p, w, 1.00167406f);
    p = fmaf(p, w, 2.83297682f);
  }
  return p * x_;
}

__device__ __forceinline__ float normal_scalar(uint32_t k0, uint32_t k1) {
  const float lo = __uint_as_float(0xBF7FFFFFu);   // nextafter(-1,0)
  float u = u01_from_bits(tf_bits_fold(k0, k1, 0u)) * 2.0f + lo;
  u = fmaxf(lo, u);
  return __uint_as_float(0x3FB504F3u) * erfinv_fast(u);  // f32(sqrt(2))
}

// ---- continue a rejected gamma chain to acceptance (carried key just rejected)
__device__ float gamma_finish(uint32_t key0, uint32_t key1, float d_, float c_) {
  float X, V, U;
  for (;;) {
    uint32_t t0, t1;
    tf2x32(key0, key1, 0u, 0u, t0, t1);
    key0 = t0; key1 = t1;
    uint32_t xk0, xk1, Uk0, Uk1;
    tf2x32(key0, key1, 0u, 1u, xk0, xk1);
    tf2x32(key0, key1, 0u, 2u, Uk0, Uk1);
    float xx, vv;
    for (;;) {
      uint32_t xs0, xs1;
      tf2x32(xk0, xk1, 0u, 1u, xs0, xs1);
      xx = normal_scalar(xs0, xs1);
      vv = 1.0f + xx * c_;
      if (vv > 0.0f) break;
      uint32_t a0, a1;
      tf2x32(xk0, xk1, 0u, 0u, a0, a1);
      xk0 = a0; xk1 = a1;
    }
    X = xx * xx;
    V = (vv * vv) * vv;
    U = u01_from_bits(tf_bits_fold(Uk0, Uk1, 0u));
    const bool rej = (U >= 1.0f - 0.0331f * (X * X) * (X * X)) &&
                     (__logf(U) >= 0.5f * X + d_ * ((1.0f - V) + __logf(V)));
    if (!rej) break;
  }
  return d_ * V;
}

// ---- generic _gamma_one (Dirichlet + alpha<1 fallback) ---------------------
__device__ float gamma_core(uint32_t key0, uint32_t key1, float d_, float c_,
                            float alpha_orig) {
  uint32_t nk0, nk1;
  tf2x32(key0, key1, 0u, 0u, nk0, nk1);
  const bool boost = alpha_orig >= 1.0f;
  float u_boost = 0.0f;
  if (!boost) {
    uint32_t sk0, sk1;
    tf2x32(key0, key1, 0u, 1u, sk0, sk1);
    u_boost = u01_from_bits(tf_bits_fold(sk0, sk1, 0u));
  }
  key0 = nk0; key1 = nk1;

  float X, V, U;
  for (;;) {
    uint32_t xk0, xk1, Uk0, Uk1;
    tf2x32(key0, key1, 0u, 1u, xk0, xk1);
    tf2x32(key0, key1, 0u, 2u, Uk0, Uk1);
    float xx, vv;
    for (;;) {
      uint32_t xs0, xs1;
      tf2x32(xk0, xk1, 0u, 1u, xs0, xs1);
      xx = normal_scalar(xs0, xs1);
      vv = 1.0f + xx * c_;
      if (vv > 0.0f) break;
      uint32_t t0, t1;
      tf2x32(xk0, xk1, 0u, 0u, t0, t1);
      xk0 = t0; xk1 = t1;
    }
    X = xx * xx;
    V = (vv * vv) * vv;
    U = u01_from_bits(tf_bits_fold(Uk0, Uk1, 0u));
    const bool rej = (U >= 1.0f - 0.0331f * (X * X) * (X * X)) &&
                     (__logf(U) >= 0.5f * X + d_ * ((1.0f - V) + __logf(V)));
    if (!rej) break;
    uint32_t t0, t1;
    tf2x32(key0, key1, 0u, 0u, t0, t1);
    key0 = t0; key1 = t1;
  }
  float sample = d_ * V;
  if (!boost) sample *= powf(u_boost, 1.0f / alpha_orig);
  return sample;
}

// ---------------- digamma (recurrence + asymptotic; x>=2 here) --------------
__device__ float digamma_f(float xf) {
  float r = 0.0f;
  while (xf < 6.0f) { r -= 1.0f / xf; xf += 1.0f; }
  const float inv = 1.0f / xf, inv2 = inv * inv;
  const float series = inv2 * (1.0f / 12.0f - inv2 * (1.0f / 120.0f - inv2 * (1.0f / 252.0f)));
  return r + logf(xf) - 0.5f * inv - series;
}

// ---------------- prep: KL term -> klout[0]; packed transposed table --------
__global__ __launch_bounds__(256) void prep_kernel(
    const float* __restrict__ locs, const float* __restrict__ scales,
    const float* __restrict__ alpha, const float* __restrict__ beta,
    const float* __restrict__ counts, float* __restrict__ klout,
    float* __restrict__ tab) {
  const int tid = threadIdx.x;
  __shared__ double red[256];
  double acc = 0.0;
  for (int i = tid; i < KMIX * DDIM; i += 256) {
    const int k = i >> 6, dd = i & 63;
    const float lc = locs[i], sc = scales[i], a = alpha[i], b = beta[i];
    acc += (double)(-logf(sc) + 0.5f * (sc * sc + lc * lc) - 0.5f);
    const float t = (a - 5.0f) * digamma_f(a) - lgammaf(a) + lgammaf(5.0f)
                  + 5.0f * (logf(b) - logf(5.0f)) + a * (5.0f - b) / b;
    acc += (double)t;
    const float al = (a >= 1.0f) ? a : a + 1.0f;
    const float d_ = al - 0.33333334f;                  // bit-identical to gamma path
    const float c_ = 0.33333334f / sqrtf(d_);
    float* e = tab + ((size_t)((dd << 6) | k)) * TSTR;
    e[0] = lc; e[1] = sc; e[2] = c_; e[3] = d_;
    e[4] = 1.0f / b; e[5] = a; e[6] = 0.0f; e[7] = 0.0f;
  }
  red[tid] = acc;
  __syncthreads();
  for (int s = 128; s > 0; s >>= 1) {
    if (tid < s) red[tid] += red[tid + s];
    __syncthreads();
  }
  if (tid == 0) {
    double c0 = 0.0;
    for (int k = 0; k < KMIX; ++k) c0 += (double)counts[k];
    const float c0f = (float)c0;
    double th = (double)lgammaf(c0f) - (double)lgammaf(2.0f * (float)KMIX);
    for (int k = 0; k < KMIX; ++k) {
      const float ck = counts[k];
      th += -(double)lgammaf(ck) + (double)lgammaf(2.0f);
      th += (double)((ck - 2.0f) * (digamma_f(ck) - digamma_f(c0f)));
    }
    const double kl = red[0] + th;
    klout[0] = (float)(kl / (double)NPTS);
  }
}

// ---------------- main: 1 wave per n; lane = k; deferred-retry queue --------
__global__ __launch_bounds__(256) void gmm_main(
    const float* __restrict__ x, const float* __restrict__ counts,
    const float* __restrict__ klbuf, const float* __restrict__ tab,
    float* __restrict__ out,
    uint32_t ke0, uint32_t ke1, uint32_t kg0, uint32_t kg1,
    uint32_t kd0, uint32_t kd1) {
  const int w = threadIdx.x >> 6;
  const int lane = threadIdx.x & 63;
  const int n = blockIdx.x * 4 + w;
  const int k = lane;

  __shared__ float xsh[4][DDIM];
  __shared__ uint32_t q[4][64][LSTR];   // per-lane deferred-retry queue (padded)
  xsh[w][lane] = x[n * DDIM + lane];
  __syncthreads();
  uint32_t* const myq = &q[w][lane][0];
  int cnt = 0;

  const uint32_t nk = (uint32_t)(n * KMIX + k);

  // Dirichlet gamma: gd ~ Gamma(counts[k]); key = threefry(kd, (0, nk))
  float gd;
  {
    const float ck = counts[k];
    const float al = (ck >= 1.0f) ? ck : ck + 1.0f;
    const float d_ = al - 0.33333334f;
    const float c_ = 0.33333334f / sqrtf(d_);
    uint32_t a0, a1; tf2x32(kd0, kd1, 0u, nk, a0, a1);
    gd = gamma_core(a0, a1, d_, c_, ck);
  }
  float ssum = gd;
  #pragma unroll
  for (int m = 32; m >= 1; m >>= 1) ssum += __shfl_xor(ssum, m, 64);
  const float log_theta = __logf(__fdividef(gd, ssum));

  float sum_z2 = 0.0f;
  float prod_r = 1.0f;
  const uint32_t jbase = nk << 6;
  const float lo = __uint_as_float(0xBF7FFFFFu);

  #pragma unroll 1
  for (int dd = 0; dd < DDIM; ++dd) {
    const float* e = tab + ((size_t)((dd << 6) | k)) * TSTR;
    const float4 t0 = *(const float4*)(e);      // {loc, scale, c_, d_}
    const float4 t1 = *(const float4*)(e + 4);  // {rcpb, alpha, 0, 0}
    const uint32_t j = jbase + (uint32_t)dd;

    // eps ~ Normal (counter-mode bits over (N,K,D) from ke) — output-only path
    float u = u01_from_bits(tf_bits_fold(ke0, ke1, j)) * 2.0f + lo;
    u = fmaxf(lo, u);
    const float eps = __uint_as_float(0x3FB504F3u) * erfinv_fast(u);
    const float mu = t0.x + t0.y * eps;
    const float diff = xsh[w][dd] - mu;
    const float diff2 = diff * diff;

    // gamma: first attempt inline; defer retries
    uint32_t gk0, gk1; tf2x32(kg0, kg1, 0u, j, gk0, gk1);
    float g;
    bool deferred = false;
    if (__builtin_expect(t1.y < 1.0f, 0)) {
      g = gamma_core(gk0, gk1, t0.w, t0.z, t1.y);   // never taken for this data
    } else {
      uint32_t key0, key1;
      tf2x32(gk0, gk1, 0u, 0u, key0, key1);         // initial split advance
      uint32_t xk0, xk1, Uk0, Uk1;
      tf2x32(key0, key1, 0u, 1u, xk0, xk1);
      tf2x32(key0, key1, 0u, 2u, Uk0, Uk1);
      float xx, vv;
      for (;;) {
        uint32_t xs0, xs1;
        tf2x32(xk0, xk1, 0u, 1u, xs0, xs1);
        xx = normal_scalar(xs0, xs1);
        vv = 1.0f + xx * t0.z;
        if (vv > 0.0f) break;
        uint32_t a0, a1;
        tf2x32(xk0, xk1, 0u, 0u, a0, a1);
        xk0 = a0; xk1 = a1;
      }
      const float X = xx * xx;
      const float V = (vv * vv) * vv;
      const float U = u01_from_bits(tf_bits_fold(Uk0, Uk1, 0u));
      const bool rej = (U >= 1.0f - 0.0331f * (X * X) * (X * X)) &&
                       (__logf(U) >= 0.5f * X + t0.w * ((1.0f - V) + __logf(V)));
      if (!rej) {
        g = t0.w * V;
      } else if (cnt < QCAP) {
        uint32_t* s = myq + cnt * QW;
        s[0] = key0; s[1] = key1;
        s[2] = __float_as_uint(diff2); s[3] = (uint32_t)dd;
        ++cnt;
        deferred = true;
      } else {
        g = gamma_finish(key0, key1, t0.w, t0.z);   // rare overflow fallback
      }
    }
    if (!deferred) {
      const float r = g * t1.x;                     // g * (1/beta)
      sum_z2 += diff2 * r;
      prod_r *= r;
    }
  }

  // drain deferred retries: static slot index, dense lanes
  #pragma unroll 1
  for (int s = 0; s < QCAP; ++s) {
    if (__any(cnt > s)) {
      if (cnt > s) {
        const uint32_t* eq = myq + s * QW;
        const uint32_t K0 = eq[0], K1 = eq[1];
        const float diff2 = __uint_as_float(eq[2]);
        const int dq = (int)eq[3];
        const float* e = tab + ((size_t)((dq << 6) | k)) * TSTR;
        const float4 t0 = *(const float4*)(e);      // {loc, scale, c_, d_}
        const float rcpb = e[4];
        const float g = gamma_finish(K0, K1, t0.w, t0.z);
        const float r = g * rcpb;
        sum_z2 += diff2 * r;
        prod_r *= r;
      }
    }
  }

  const float comp_lp = -0.5f * sum_z2 + 0.5f * __logf(prod_r) - 58.81206612509905f;
  float v = log_theta + comp_lp;

  float m = v;
  #pragma unroll
  for (int mm = 32; mm >= 1; mm >>= 1) m = fmaxf(m, __shfl_xor(m, mm, 64));
  float e2 = __expf(v - m);
  #pragma unroll
  for (int mm = 32; mm >= 1; mm >>= 1) e2 += __shfl_xor(e2, mm, 64);
  const float log_lik = m + __logf(e2);

  if (lane == 0) out[n] = klbuf[0] - log_lik;
}

extern "C" void kernel_launch(void* const* d_in, const int* in_sizes, int n_in,
                              void* d_out, int out_size, void* d_ws, size_t ws_size,
                              hipStream_t stream) {
  (void)in_sizes; (void)n_in; (void)out_size; (void)ws_size;
  const float* x      = (const float*)d_in[0];
  const float* locs   = (const float*)d_in[1];
  const float* scales = (const float*)d_in[2];
  const float* alpha  = (const float*)d_in[3];
  const float* beta   = (const float*)d_in[4];
  const float* counts = (const float*)d_in[5];
  float* out   = (float*)d_out;
  float* klbuf = (float*)d_ws;
  float* tab   = (float*)((char*)d_ws + 1024);   // 4096 * 8 floats = 128 KiB

  uint32_t ke0, ke1, kg0, kg1, kd0, kd1;
  tf2x32(0u, 42u, 0u, 0u, ke0, ke1);
  tf2x32(0u, 42u, 0u, 1u, kg0, kg1);
  tf2x32(0u, 42u, 0u, 2u, kd0, kd1);

  hipLaunchKernelGGL(prep_kernel, dim3(1), dim3(256), 0, stream,
                     locs, scales, alpha, beta, counts, klbuf, tab);
  hipLaunchKernelGGL(gmm_main, dim3(NPTS / 4), dim3(256), 0, stream,
                     x, counts, klbuf, tab, out,
                     ke0, ke1, kg0, kg1, kd0, kd1);
}

// Round 5
// 622.181 us; speedup vs baseline: 1.7996x; 1.0147x over previous
//
#include <hip/hip_runtime.h>
#include <stdint.h>

// Keep default mul/add unfused (accept-test boundaries); safe spots use fmaf explicitly.
#pragma clang fp contract(off)

#define NPTS 8192
#define KMIX 64
#define DDIM 64
#define TSTR 8    // param table entry stride (floats)
#define QCAP 4    // deferred-retry slots per lane
#define QW   4    // words per slot: key0,key1,diff2,dd
#define LSTR 18   // per-lane queue stride in words (2-way bank alias max = free)

// ---------------- threefry2x32 (exact transcription of jax/_src/prng.py) ----
__host__ __device__ __forceinline__ void tf2x32(uint32_t k0, uint32_t k1,
                                                uint32_t x0, uint32_t x1,
                                                uint32_t& o0, uint32_t& o1) {
  const uint32_t ks2 = k0 ^ k1 ^ 0x1BD11BDAu;
#define TF_R(r) { x0 += x1; x1 = (x1 << (r)) | (x1 >> (32 - (r))); x1 ^= x0; }
  x0 += k0; x1 += k1;
  TF_R(13) TF_R(15) TF_R(26) TF_R(6)
  x0 += k1; x1 += ks2 + 1u;
  TF_R(17) TF_R(29) TF_R(16) TF_R(24)
  x0 += ks2; x1 += k0 + 2u;
  TF_R(13) TF_R(15) TF_R(26) TF_R(6)
  x0 += k0; x1 += k1 + 3u;
  TF_R(17) TF_R(29) TF_R(16) TF_R(24)
  x0 += k1; x1 += ks2 + 4u;
  TF_R(13) TF_R(15) TF_R(26) TF_R(6)
  x0 += ks2; x1 += k0 + 5u;
#undef TF_R
  o0 = x0; o1 = x1;
}

__device__ __forceinline__ uint32_t tf_bits_fold(uint32_t k0, uint32_t k1, uint32_t j) {
  uint32_t a, b; tf2x32(k0, k1, 0u, j, a, b); return a ^ b;
}

__device__ __forceinline__ float u01_from_bits(uint32_t bits) {
  return __uint_as_float((bits >> 9) | 0x3f800000u) - 1.0f;
}

// ---------------- fast erfinv: Giles constants, fmaf chain, hw log ----------
__device__ __forceinline__ float erfinv_fast(float x_) {
  float w = -__logf(1.0f - x_ * x_);
  float p;
  if (w < 5.0f) {
    w = w - 2.5f;
    p = fmaf(2.81022636e-08f, w, 3.43273939e-07f);
    p = fmaf(p, w, -3.5233877e-06f);
    p = fmaf(p, w, -4.39150654e-06f);
    p = fmaf(p, w, 0.00021858087f);
    p = fmaf(p, w, -0.00125372503f);
    p = fmaf(p, w, -0.00417768164f);
    p = fmaf(p, w, 0.246640727f);
    p = fmaf(p, w, 1.50140941f);
  } else {
    w = __builtin_amdgcn_sqrtf(w) - 3.0f;   // rare tail branch; ulp-level only
    p = fmaf(-0.000200214257f, w, 0.000100950558f);
    p = fmaf(p, w, 0.00134934322f);
    p = fmaf(p, w, -0.00367342844f);
    p = fmaf(p, w, 0.00573950773f);
    p = fmaf(p, w, -0.0076224613f);
    p = fmaf(p, w, 0.00943887047f);
    p = fmaf(p, w, 1.00167406f);
    p = fmaf(p, w, 2.83297682f);
  }
  return p * x_;
}

__device__ __forceinline__ float normal_scalar(uint32_t k0, uint32_t k1) {
  const float lo = __uint_as_float(0xBF7FFFFFu);   // nextafter(-1,0)
  // fmaf(u,2,lo) is bit-identical to u*2+lo (x2 is exact) — safe on accept path
  float u = fmaf(u01_from_bits(tf_bits_fold(k0, k1, 0u)), 2.0f, lo);
  u = fmaxf(lo, u);
  return __uint_as_float(0x3FB504F3u) * erfinv_fast(u);  // f32(sqrt(2))
}

// ---- continue a rejected gamma chain to acceptance (carried key just rejected)
__device__ float gamma_finish(uint32_t key0, uint32_t key1, float d_, float c_) {
  float X, V, U;
  for (;;) {
    uint32_t t0, t1;
    tf2x32(key0, key1, 0u, 0u, t0, t1);
    key0 = t0; key1 = t1;
    uint32_t xk0, xk1, Uk0, Uk1;
    tf2x32(key0, key1, 0u, 1u, xk0, xk1);
    tf2x32(key0, key1, 0u, 2u, Uk0, Uk1);
    float xx, vv;
    for (;;) {
      uint32_t xs0, xs1;
      tf2x32(xk0, xk1, 0u, 1u, xs0, xs1);
      xx = normal_scalar(xs0, xs1);
      vv = 1.0f + xx * c_;
      if (vv > 0.0f) break;
      uint32_t a0, a1;
      tf2x32(xk0, xk1, 0u, 0u, a0, a1);
      xk0 = a0; xk1 = a1;
    }
    X = xx * xx;
    V = (vv * vv) * vv;
    U = u01_from_bits(tf_bits_fold(Uk0, Uk1, 0u));
    // EXACT round-0 accept expressions — do not modify.
    const bool rej = (U >= 1.0f - 0.0331f * (X * X) * (X * X)) &
                     (__logf(U) >= 0.5f * X + d_ * ((1.0f - V) + __logf(V)));
    if (!rej) break;
  }
  return d_ * V;
}

// ---- generic _gamma_one — used for Dirichlet draw only (ck>=1 path hot) ----
__device__ float gamma_core(uint32_t key0, uint32_t key1, float d_, float c_,
                            float alpha_orig) {
  uint32_t nk0, nk1;
  tf2x32(key0, key1, 0u, 0u, nk0, nk1);
  const bool boost = alpha_orig >= 1.0f;
  float u_boost = 0.0f;
  if (!boost) {
    uint32_t sk0, sk1;
    tf2x32(key0, key1, 0u, 1u, sk0, sk1);
    u_boost = u01_from_bits(tf_bits_fold(sk0, sk1, 0u));
  }
  key0 = nk0; key1 = nk1;

  float X, V, U;
  for (;;) {
    uint32_t xk0, xk1, Uk0, Uk1;
    tf2x32(key0, key1, 0u, 1u, xk0, xk1);
    tf2x32(key0, key1, 0u, 2u, Uk0, Uk1);
    float xx, vv;
    for (;;) {
      uint32_t xs0, xs1;
      tf2x32(xk0, xk1, 0u, 1u, xs0, xs1);
      xx = normal_scalar(xs0, xs1);
      vv = 1.0f + xx * c_;
      if (vv > 0.0f) break;
      uint32_t t0, t1;
      tf2x32(xk0, xk1, 0u, 0u, t0, t1);
      xk0 = t0; xk1 = t1;
    }
    X = xx * xx;
    V = (vv * vv) * vv;
    U = u01_from_bits(tf_bits_fold(Uk0, Uk1, 0u));
    const bool rej = (U >= 1.0f - 0.0331f * (X * X) * (X * X)) &
                     (__logf(U) >= 0.5f * X + d_ * ((1.0f - V) + __logf(V)));
    if (!rej) break;
    uint32_t t0, t1;
    tf2x32(key0, key1, 0u, 0u, t0, t1);
    key0 = t0; key1 = t1;
  }
  float sample = d_ * V;
  if (!boost) sample *= powf(u_boost, 1.0f / alpha_orig);
  return sample;
}

// ---------------- digamma (recurrence + asymptotic; x>=2 here) --------------
__device__ float digamma_f(float xf) {
  float r = 0.0f;
  while (xf < 6.0f) { r -= 1.0f / xf; xf += 1.0f; }
  const float inv = 1.0f / xf, inv2 = inv * inv;
  const float series = inv2 * (1.0f / 12.0f - inv2 * (1.0f / 120.0f - inv2 * (1.0f / 252.0f)));
  return r + logf(xf) - 0.5f * inv - series;
}

// ---------------- prep: KL term -> klout[0]; packed transposed table --------
__global__ __launch_bounds__(256) void prep_kernel(
    const float* __restrict__ locs, const float* __restrict__ scales,
    const float* __restrict__ alpha, const float* __restrict__ beta,
    const float* __restrict__ counts, float* __restrict__ klout,
    float* __restrict__ tab) {
  const int tid = threadIdx.x;
  __shared__ double red[256];
  double acc = 0.0;
  for (int i = tid; i < KMIX * DDIM; i += 256) {
    const int k = i >> 6, dd = i & 63;
    const float lc = locs[i], sc = scales[i], a = alpha[i], b = beta[i];
    acc += (double)(-logf(sc) + 0.5f * (sc * sc + lc * lc) - 0.5f);
    const float t = (a - 5.0f) * digamma_f(a) - lgammaf(a) + lgammaf(5.0f)
                  + 5.0f * (logf(b) - logf(5.0f)) + a * (5.0f - b) / b;
    acc += (double)t;
    const float al = (a >= 1.0f) ? a : a + 1.0f;
    const float d_ = al - 0.33333334f;                  // bit-identical to gamma path
    const float c_ = 0.33333334f / sqrtf(d_);
    float* e = tab + ((size_t)((dd << 6) | k)) * TSTR;
    e[0] = lc; e[1] = sc; e[2] = c_; e[3] = d_;
    e[4] = 1.0f / b; e[5] = a; e[6] = 0.0f; e[7] = 0.0f;
  }
  red[tid] = acc;
  __syncthreads();
  for (int s = 128; s > 0; s >>= 1) {
    if (tid < s) red[tid] += red[tid + s];
    __syncthreads();
  }
  if (tid == 0) {
    double c0 = 0.0;
    for (int k = 0; k < KMIX; ++k) c0 += (double)counts[k];
    const float c0f = (float)c0;
    double th = (double)lgammaf(c0f) - (double)lgammaf(2.0f * (float)KMIX);
    for (int k = 0; k < KMIX; ++k) {
      const float ck = counts[k];
      th += -(double)lgammaf(ck) + (double)lgammaf(2.0f);
      th += (double)((ck - 2.0f) * (digamma_f(ck) - digamma_f(c0f)));
    }
    const double kl = red[0] + th;
    klout[0] = (float)(kl / (double)NPTS);
  }
}

// ---------------- main: 1 wave per n; lane = k; deferred-retry queue --------
__global__ __launch_bounds__(256) void gmm_main(
    const float* __restrict__ x, const float* __restrict__ counts,
    const float* __restrict__ klbuf, const float* __restrict__ tab,
    float* __restrict__ out,
    uint32_t ke0, uint32_t ke1, uint32_t kg0, uint32_t kg1,
    uint32_t kd0, uint32_t kd1) {
  const int w = threadIdx.x >> 6;
  const int lane = threadIdx.x & 63;
  const int n = blockIdx.x * 4 + w;
  const int k = lane;

  __shared__ float xsh[4][DDIM];
  __shared__ uint32_t q[4][64][LSTR];   // 18 KiB: total LDS <= 20 KiB -> 8 blocks/CU
  xsh[w][lane] = x[n * DDIM + lane];
  __syncthreads();
  uint32_t* const myq = &q[w][lane][0];
  int cnt = 0;

  const uint32_t nk = (uint32_t)(n * KMIX + k);

  // Dirichlet gamma: gd ~ Gamma(counts[k]); key = threefry(kd, (0, nk))
  float gd;
  {
    const float ck = counts[k];
    const float al = (ck >= 1.0f) ? ck : ck + 1.0f;
    const float d_ = al - 0.33333334f;
    const float c_ = 0.33333334f / sqrtf(d_);
    uint32_t a0, a1; tf2x32(kd0, kd1, 0u, nk, a0, a1);
    gd = gamma_core(a0, a1, d_, c_, ck);
  }
  float ssum = gd;
  #pragma unroll
  for (int m = 32; m >= 1; m >>= 1) ssum += __shfl_xor(ssum, m, 64);
  const float log_theta = __logf(__fdividef(gd, ssum));

  float sum_z2 = 0.0f;
  float prod_r = 1.0f;
  const uint32_t jbase = nk << 6;
  const float lo = __uint_as_float(0xBF7FFFFFu);
  // strength-reduced param pointer: entry (dd<<6)|k, advances 64*TSTR floats/dd
  const float* ep = tab + (size_t)k * TSTR;

  #pragma unroll 1
  for (int dd = 0; dd < DDIM; ++dd, ep += (size_t)KMIX * TSTR) {
    const float4 t0 = *(const float4*)(ep);      // {loc, scale, c_, d_}
    const float rcpb = ep[4];
    const uint32_t j = jbase + (uint32_t)dd;

    // eps ~ Normal (counter-mode bits over (N,K,D) from ke) — output-only path
    float u = fmaf(u01_from_bits(tf_bits_fold(ke0, ke1, j)), 2.0f, lo);
    u = fmaxf(lo, u);
    const float eps = __uint_as_float(0x3FB504F3u) * erfinv_fast(u);
    const float mu = fmaf(t0.y, eps, t0.x);      // output-only: fuse ok
    const float diff = xsh[w][dd] - mu;
    const float diff2 = diff * diff;

    // gamma (alpha in [4,6] by construction -> boost path only):
    // first attempt inline; defer retries to compacted drain
    uint32_t gk0, gk1; tf2x32(kg0, kg1, 0u, j, gk0, gk1);
    uint32_t key0, key1;
    tf2x32(gk0, gk1, 0u, 0u, key0, key1);        // initial split advance
    uint32_t xk0, xk1, Uk0, Uk1;
    tf2x32(key0, key1, 0u, 1u, xk0, xk1);
    tf2x32(key0, key1, 0u, 2u, Uk0, Uk1);
    float xx, vv;
    for (;;) {
      uint32_t xs0, xs1;
      tf2x32(xk0, xk1, 0u, 1u, xs0, xs1);
      xx = normal_scalar(xs0, xs1);
      vv = 1.0f + xx * t0.z;
      if (vv > 0.0f) break;
      uint32_t a0, a1;
      tf2x32(xk0, xk1, 0u, 0u, a0, a1);
      xk0 = a0; xk1 = a1;
    }
    const float X = xx * xx;
    const float V = (vv * vv) * vv;
    const float U = u01_from_bits(tf_bits_fold(Uk0, Uk1, 0u));
    // EXACT round-0 accept expressions — do not modify.
    const bool rej = (U >= 1.0f - 0.0331f * (X * X) * (X * X)) &
                     (__logf(U) >= 0.5f * X + t0.w * ((1.0f - V) + __logf(V)));
    bool deferred = false;
    float g = t0.w * V;
    if (rej) {
      if (cnt < QCAP) {
        uint32_t* s = myq + cnt * QW;
        s[0] = key0; s[1] = key1;
        s[2] = __float_as_uint(diff2); s[3] = (uint32_t)dd;
        ++cnt;
        deferred = true;
      } else {
        g = gamma_finish(key0, key1, t0.w, t0.z); // rare overflow fallback
      }
    }
    if (!deferred) {
      const float r = g * rcpb;                   // g * (1/beta)
      sum_z2 = fmaf(diff2, r, sum_z2);            // output-only: fuse ok
      prod_r *= r;                                // sum(log r) -> log(prod r)
    }
  }

  // drain deferred retries: static slot index, dense lanes
  #pragma unroll 1
  for (int s = 0; s < QCAP; ++s) {
    if (__any(cnt > s)) {
      if (cnt > s) {
        const uint32_t* eq = myq + s * QW;
        const uint32_t K0 = eq[0], K1 = eq[1];
        const float diff2 = __uint_as_float(eq[2]);
        const int dq = (int)eq[3];
        const float* e = tab + ((size_t)((dq << 6) | k)) * TSTR;
        const float4 t0 = *(const float4*)(e);
        const float rcpb = e[4];
        const float g = gamma_finish(K0, K1, t0.w, t0.z);
        const float r = g * rcpb;
        sum_z2 = fmaf(diff2, r, sum_z2);
        prod_r *= r;
      }
    }
  }

  const float comp_lp = -0.5f * sum_z2 + 0.5f * __logf(prod_r) - 58.81206612509905f;
  float v = log_theta + comp_lp;

  float m = v;
  #pragma unroll
  for (int mm = 32; mm >= 1; mm >>= 1) m = fmaxf(m, __shfl_xor(m, mm, 64));
  float e2 = __expf(v - m);
  #pragma unroll
  for (int mm = 32; mm >= 1; mm >>= 1) e2 += __shfl_xor(e2, mm, 64);
  const float log_lik = m + __logf(e2);

  if (lane == 0) out[n] = klbuf[0] - log_lik;
}

extern "C" void kernel_launch(void* const* d_in, const int* in_sizes, int n_in,
                              void* d_out, int out_size, void* d_ws, size_t ws_size,
                              hipStream_t stream) {
  (void)in_sizes; (void)n_in; (void)out_size; (void)ws_size;
  const float* x      = (const float*)d_in[0];
  const float* locs   = (const float*)d_in[1];
  const float* scales = (const float*)d_in[2];
  const float* alpha  = (const float*)d_in[3];
  const float* beta   = (const float*)d_in[4];
  const float* counts = (const float*)d_in[5];
  float* out   = (float*)d_out;
  float* klbuf = (float*)d_ws;
  float* tab   = (float*)((char*)d_ws + 1024);   // 4096 * 8 floats = 128 KiB

  uint32_t ke0, ke1, kg0, kg1, kd0, kd1;
  tf2x32(0u, 42u, 0u, 0u, ke0, ke1);
  tf2x32(0u, 42u, 0u, 1u, kg0, kg1);
  tf2x32(0u, 42u, 0u, 2u, kd0, kd1);

  hipLaunchKernelGGL(prep_kernel, dim3(1), dim3(256), 0, stream,
                     locs, scales, alpha, beta, counts, klbuf, tab);
  hipLaunchKernelGGL(gmm_main, dim3(NPTS / 4), dim3(256), 0, stream,
                     x, counts, klbuf, tab, out,
                     ke0, ke1, kg0, kg1, kd0, kd1);
}